// Round 2
// baseline (222.424 us; speedup 1.0000x reference)
//
#include <hip/hip_runtime.h>
#include <math.h>

typedef short v8s __attribute__((ext_vector_type(8)));
typedef float v4f __attribute__((ext_vector_type(4)));
typedef unsigned short v4u __attribute__((ext_vector_type(4)));

#define MFMA(a, b, c) __builtin_amdgcn_mfma_f32_16x16x32_bf16((a), (b), (c), 0, 0, 0)

__device__ __forceinline__ unsigned short f2bf(float f) {
    unsigned int u = __builtin_bit_cast(unsigned int, f);
    u += 0x7fffu + ((u >> 16) & 1u);   // round-to-nearest-even
    return (unsigned short)(u >> 16);
}
__device__ __forceinline__ float bf2f(unsigned short h) {
    return __builtin_bit_cast(float, ((unsigned int)h) << 16);
}

// ---------------------------------------------------------------- k_prep ----
__global__ __launch_bounds__(256) void k_prep(
    const float* __restrict__ Ww, const float* __restrict__ Wb,
    const float* __restrict__ gamma, const float* __restrict__ beta,
    const float* __restrict__ mean, const float* __restrict__ var,
    unsigned short* __restrict__ Wt, float* __restrict__ sc, float* __restrict__ bi)
{
    int t = threadIdx.x;
    #pragma unroll
    for (int rep = 0; rep < 32; ++rep) {
        int idx = rep * 256 + t;          // 64*128 = 8192 elements
        int d = idx >> 7, c = idx & 127;  // W_w is [64][128], coalesced read
        Wt[c * 64 + d] = f2bf(Ww[idx]);
    }
    if (t < 128) {
        float inv = gamma[t] * rsqrtf(var[t] + 1e-4f);
        sc[t] = inv;
        bi[t] = (Wb[t] - mean[t]) * inv + beta[t];
    }
}

// ---------------------------------------------------------------- k_proj ----
// fp32 projections; theta/phi written as SPLIT bf16 (hi + residual-lo) for
// high-precision QK^T; g transposed bf16 gT[b][64][4096].
__global__ __launch_bounds__(256) void k_proj(
    const float* __restrict__ x,
    const float* __restrict__ tw, const float* __restrict__ tb,
    const float* __restrict__ pw, const float* __restrict__ pb,
    const float* __restrict__ gw, const float* __restrict__ gb,
    unsigned short* __restrict__ theta_hi, unsigned short* __restrict__ theta_lo,
    unsigned short* __restrict__ phi_hi, unsigned short* __restrict__ phi_lo,
    unsigned short* __restrict__ gT)
{
    __shared__ __align__(16) float xl[64][132];   // +4 pad
    __shared__ __align__(16) float wl[64][68];
    const int t = threadIdx.x;
    const int tok0 = blockIdx.x * 64;

    #pragma unroll
    for (int rep = 0; rep < 8; ++rep) {           // stage x tile [64][128]
        int chunk = rep * 256 + t;
        int tk = chunk >> 5, k = (chunk & 31) * 4;
        *(float4*)&xl[tk][k] = *(const float4*)(x + (size_t)(tok0 + tk) * 128 + k);
    }
    const int tg = t >> 4, og = t & 15;

    for (int p = 0; p < 3; ++p) {
        const float* wmat = (p == 0) ? tw : (p == 1) ? pw : gw;
        const float* bias = (p == 0) ? tb : (p == 1) ? pb : gb;
        float acc[4][4] = {};
        #pragma unroll
        for (int kh = 0; kh < 2; ++kh) {
            __syncthreads();                      // prev compute done
            #pragma unroll
            for (int rep = 0; rep < 4; ++rep) {   // stage W half [64][64]
                int chunk = rep * 256 + t;
                int kk = chunk >> 4, o = (chunk & 15) * 4;
                *(float4*)&wl[kk][o] = *(const float4*)(wmat + (kh * 64 + kk) * 64 + o);
            }
            __syncthreads();
            #pragma unroll 4
            for (int k = 0; k < 64; ++k) {
                float4 wv = *(const float4*)&wl[k][og * 4];
                #pragma unroll
                for (int i = 0; i < 4; ++i) {
                    float xv = xl[tg * 4 + i][kh * 64 + k];
                    acc[i][0] = fmaf(xv, wv.x, acc[i][0]);
                    acc[i][1] = fmaf(xv, wv.y, acc[i][1]);
                    acc[i][2] = fmaf(xv, wv.z, acc[i][2]);
                    acc[i][3] = fmaf(xv, wv.w, acc[i][3]);
                }
            }
        }
        float4 bv = *(const float4*)(bias + og * 4);
        const float bvv[4] = {bv.x, bv.y, bv.z, bv.w};
        if (p < 2) {
            unsigned short* dh = (p == 0) ? theta_hi : phi_hi;
            unsigned short* dl = (p == 0) ? theta_lo : phi_lo;
            #pragma unroll
            for (int i = 0; i < 4; ++i) {
                int tok = tok0 + tg * 4 + i;
                v4u oh, ol;
                #pragma unroll
                for (int j = 0; j < 4; ++j) {
                    float v = acc[i][j] + bvv[j];
                    unsigned short h = f2bf(v);
                    oh[j] = h;
                    ol[j] = f2bf(v - bf2f(h));
                }
                *(v4u*)(dh + (size_t)tok * 64 + og * 4) = oh;
                *(v4u*)(dl + (size_t)tok * 64 + og * 4) = ol;
            }
        } else {
            #pragma unroll
            for (int i = 0; i < 4; ++i) {
                int tok = tok0 + tg * 4 + i;
                int bb = tok >> 12, n = tok & 4095;
                #pragma unroll
                for (int j = 0; j < 4; ++j)
                    gT[((size_t)bb * 64 + og * 4 + j) * 4096 + n] = f2bf(acc[i][j] + bvv[j]);
            }
        }
    }
}

// ---------------------------------------------------------------- k_attn ----
// Flash attention + fused epilogue. Grid (32,8) = 256 blocks (1/CU).
// 4 waves x 32 queries = 128 q/block; key tile 64; mfma 16x16x32 bf16.
// QK^T uses split bf16: S = th_hi.ph_hi + th_hi.ph_lo + th_lo.ph_hi
// A-frag: row=l&15, k=(l>>4)*8+j ; B-frag: col=l&15, k=(l>>4)*8+j ;
// D: col=l&15, row=(l>>4)*4+r
__global__ __launch_bounds__(256, 1) void k_attn(
    const unsigned short* __restrict__ theta_hi,
    const unsigned short* __restrict__ theta_lo,
    const unsigned short* __restrict__ phi_hi,
    const unsigned short* __restrict__ phi_lo,
    const unsigned short* __restrict__ gT,
    const unsigned short* __restrict__ Wt,
    const float* __restrict__ sc, const float* __restrict__ bi,
    const float* __restrict__ x, float* __restrict__ out)
{
    __shared__ __align__(16) unsigned short ph_l[64][72];    // keys x dims (hi)
    __shared__ __align__(16) unsigned short pl_l[64][72];    // keys x dims (lo)
    __shared__ __align__(16) unsigned short gT_l[64][72];    // dims x keys
    __shared__ __align__(16) unsigned short scr[4][32][72];  // per-wave P / y
    __shared__ __align__(16) unsigned short Wt_l[128][72];   // W^T bf16

    const int t = threadIdx.x;
    const int w = t >> 6, l = t & 63, hi = l >> 4, lo = l & 15;
    const int b = blockIdx.y, qb = blockIdx.x;
    const int q0 = qb * 128 + w * 32;
    const size_t tok0 = (size_t)b * 4096 + q0;

    #pragma unroll
    for (int rep = 0; rep < 4; ++rep) {          // stage W^T once
        int flat = rep * 2048 + t * 8;
        int c = flat >> 6, d = flat & 63;
        *(v8s*)&Wt_l[c][d] = *(const v8s*)(Wt + flat);
    }

    v8s thA[2][2], tlA[2][2];                    // hoisted Q fragments (hi, lo)
    #pragma unroll
    for (int mt = 0; mt < 2; ++mt)
        #pragma unroll
        for (int kc = 0; kc < 2; ++kc) {
            size_t off = (tok0 + mt * 16 + lo) * 64 + kc * 32 + hi * 8;
            thA[mt][kc] = *(const v8s*)(theta_hi + off);
            tlA[mt][kc] = *(const v8s*)(theta_lo + off);
        }

    const unsigned short* phb = phi_hi + (size_t)b * 4096 * 64;
    const unsigned short* plb = phi_lo + (size_t)b * 4096 * 64;
    const unsigned short* gTb = gT + (size_t)b * 64 * 4096;

    v4f yacc[2][4];
    float mrow[2][4], lrow[2][4];
    #pragma unroll
    for (int mt = 0; mt < 2; ++mt)
        #pragma unroll
        for (int rr = 0; rr < 4; ++rr) {
            mrow[mt][rr] = -INFINITY; lrow[mt][rr] = 0.f;
            yacc[mt][rr] = (v4f){0.f, 0.f, 0.f, 0.f};
        }

    // register prefetch of tile 0
    v8s pfH[2], pfL[2], pfG[2];
    int rB[2], cB[2];
    #pragma unroll
    for (int q = 0; q < 2; ++q) {
        int chunk = q * 256 + t;
        rB[q] = chunk >> 3; cB[q] = (chunk & 7) * 8;
        pfH[q] = *(const v8s*)(phb + (size_t)rB[q] * 64 + cB[q]);
        pfL[q] = *(const v8s*)(plb + (size_t)rB[q] * 64 + cB[q]);
        pfG[q] = *(const v8s*)(gTb + (size_t)rB[q] * 4096 + cB[q]);
    }

    for (int kt = 0; kt < 64; ++kt) {
        __syncthreads();                         // prev tile consumed
        #pragma unroll
        for (int q = 0; q < 2; ++q) {
            *(v8s*)&ph_l[rB[q]][cB[q]] = pfH[q];
            *(v8s*)&pl_l[rB[q]][cB[q]] = pfL[q];
            *(v8s*)&gT_l[rB[q]][cB[q]] = pfG[q];
        }
        __syncthreads();
        if (kt < 63) {                           // prefetch next tile under compute
            int kb2 = (kt + 1) * 64;
            #pragma unroll
            for (int q = 0; q < 2; ++q) {
                pfH[q] = *(const v8s*)(phb + (size_t)(kb2 + rB[q]) * 64 + cB[q]);
                pfL[q] = *(const v8s*)(plb + (size_t)(kb2 + rB[q]) * 64 + cB[q]);
                pfG[q] = *(const v8s*)(gTb + (size_t)rB[q] * 4096 + kb2 + cB[q]);
            }
        }
        // ---- QK^T (split precision)
        v4f S[2][4];
        #pragma unroll
        for (int s = 0; s < 4; ++s) {
            v8s bH[2], bL[2];
            #pragma unroll
            for (int kc = 0; kc < 2; ++kc) {
                bH[kc] = *(const v8s*)&ph_l[s * 16 + lo][kc * 32 + hi * 8];
                bL[kc] = *(const v8s*)&pl_l[s * 16 + lo][kc * 32 + hi * 8];
            }
            #pragma unroll
            for (int mt = 0; mt < 2; ++mt) {
                v4f a = MFMA(thA[mt][0], bH[0], ((v4f){0.f, 0.f, 0.f, 0.f}));
                a = MFMA(thA[mt][1], bH[1], a);
                a = MFMA(thA[mt][0], bL[0], a);
                a = MFMA(thA[mt][1], bL[1], a);
                a = MFMA(tlA[mt][0], bH[0], a);
                S[mt][s] = MFMA(tlA[mt][1], bH[1], a);
            }
        }
        // ---- online softmax (rows spread over 16-lane groups; 4 rows/lane/mt)
        float al[2][4];
        #pragma unroll
        for (int mt = 0; mt < 2; ++mt)
            #pragma unroll
            for (int rr = 0; rr < 4; ++rr) {
                float v = fmaxf(fmaxf(S[mt][0][rr], S[mt][1][rr]),
                                fmaxf(S[mt][2][rr], S[mt][3][rr]));
                v = fmaxf(v, __shfl_xor(v, 1));
                v = fmaxf(v, __shfl_xor(v, 2));
                v = fmaxf(v, __shfl_xor(v, 4));
                v = fmaxf(v, __shfl_xor(v, 8));
                float mo = mrow[mt][rr];
                float mn = fmaxf(mo, v);
                float a = __expf(mo - mn);       // 0 on first tile (mo=-inf)
                mrow[mt][rr] = mn;
                float p0 = __expf(S[mt][0][rr] - mn);
                float p1 = __expf(S[mt][1][rr] - mn);
                float p2 = __expf(S[mt][2][rr] - mn);
                float p3 = __expf(S[mt][3][rr] - mn);
                S[mt][0][rr] = p0; S[mt][1][rr] = p1;
                S[mt][2][rr] = p2; S[mt][3][rr] = p3;
                float sum = (p0 + p1) + (p2 + p3);
                sum += __shfl_xor(sum, 1);
                sum += __shfl_xor(sum, 2);
                sum += __shfl_xor(sum, 4);
                sum += __shfl_xor(sum, 8);
                lrow[mt][rr] = lrow[mt][rr] * a + sum;
                al[mt][rr] = a;
            }
        // ---- P -> LDS (bf16, per-wave scratch), rescale accumulator
        unsigned short* pl = &scr[w][0][0];
        #pragma unroll
        for (int mt = 0; mt < 2; ++mt)
            #pragma unroll
            for (int rr = 0; rr < 4; ++rr) {
                int m = mt * 16 + hi * 4 + rr;
                #pragma unroll
                for (int s = 0; s < 4; ++s)
                    pl[m * 72 + s * 16 + lo] = f2bf(S[mt][s][rr]);
            }
        #pragma unroll
        for (int mt = 0; mt < 2; ++mt)
            #pragma unroll
            for (int dt = 0; dt < 4; ++dt)
                #pragma unroll
                for (int rr = 0; rr < 4; ++rr)
                    yacc[mt][dt][rr] *= al[mt][rr];
        // ---- PV: y += P(32q x 64k) . g(64k x 64d)
        v8s pA[2][2];
        #pragma unroll
        for (int mt = 0; mt < 2; ++mt)
            #pragma unroll
            for (int kc = 0; kc < 2; ++kc)
                pA[mt][kc] = *(const v8s*)&scr[w][mt * 16 + lo][kc * 32 + hi * 8];
        #pragma unroll
        for (int kc = 0; kc < 2; ++kc)
            #pragma unroll
            for (int dt = 0; dt < 4; ++dt) {
                v8s gB = *(const v8s*)&gT_l[dt * 16 + lo][kc * 32 + hi * 8];
                #pragma unroll
                for (int mt = 0; mt < 2; ++mt)
                    yacc[mt][dt] = MFMA(pA[mt][kc], gB, yacc[mt][dt]);
            }
    }

    // ---- epilogue: y/l -> bf16 LDS -> wy = y @ W^T -> BN + residual
    unsigned short* yl = &scr[w][0][0];
    #pragma unroll
    for (int mt = 0; mt < 2; ++mt)
        #pragma unroll
        for (int rr = 0; rr < 4; ++rr) {
            float inv = 1.0f / lrow[mt][rr];
            int m = mt * 16 + hi * 4 + rr;
            #pragma unroll
            for (int dt = 0; dt < 4; ++dt)
                yl[m * 72 + dt * 16 + lo] = f2bf(yacc[mt][dt][rr] * inv);
        }
    v8s yA[2][2];
    #pragma unroll
    for (int mt = 0; mt < 2; ++mt)
        #pragma unroll
        for (int kc = 0; kc < 2; ++kc)
            yA[mt][kc] = *(const v8s*)&scr[w][mt * 16 + lo][kc * 32 + hi * 8];

    const float* xb = x + tok0 * 128;
    float* ob = out + tok0 * 128;
    #pragma unroll
    for (int ct = 0; ct < 8; ++ct) {
        v8s wB0 = *(const v8s*)&Wt_l[ct * 16 + lo][hi * 8];
        v8s wB1 = *(const v8s*)&Wt_l[ct * 16 + lo][32 + hi * 8];
        int c = ct * 16 + lo;
        float scc = sc[c], bic = bi[c];
        #pragma unroll
        for (int mt = 0; mt < 2; ++mt) {
            v4f wy = MFMA(yA[mt][0], wB0, ((v4f){0.f, 0.f, 0.f, 0.f}));
            wy = MFMA(yA[mt][1], wB1, wy);
            #pragma unroll
            for (int rr = 0; rr < 4; ++rr) {
                int m = mt * 16 + hi * 4 + rr;
                ob[(size_t)m * 128 + c] = wy[rr] * scc + bic + xb[(size_t)m * 128 + c];
            }
        }
    }
}

// ------------------------------------------------------------------ launch --
extern "C" void kernel_launch(void* const* d_in, const int* in_sizes, int n_in,
                              void* d_out, int out_size, void* d_ws, size_t ws_size,
                              hipStream_t stream) {
    const float* x     = (const float*)d_in[0];
    const float* tw    = (const float*)d_in[1];
    const float* tb    = (const float*)d_in[2];
    const float* pw    = (const float*)d_in[3];
    const float* pb    = (const float*)d_in[4];
    const float* gw    = (const float*)d_in[5];
    const float* gb    = (const float*)d_in[6];
    const float* Ww    = (const float*)d_in[7];
    const float* Wb    = (const float*)d_in[8];
    const float* gamma = (const float*)d_in[9];
    const float* beta  = (const float*)d_in[10];
    const float* mean  = (const float*)d_in[11];
    const float* var   = (const float*)d_in[12];

    char* ws = (char*)d_ws;
    unsigned short* theta_hi = (unsigned short*)ws;                   // 4 MB
    unsigned short* theta_lo = (unsigned short*)(ws + (4u << 20));    // 4 MB
    unsigned short* phi_hi   = (unsigned short*)(ws + (8u << 20));    // 4 MB
    unsigned short* phi_lo   = (unsigned short*)(ws + (12u << 20));   // 4 MB
    unsigned short* gT       = (unsigned short*)(ws + (16u << 20));   // 4 MB
    unsigned short* Wt       = (unsigned short*)(ws + (20u << 20));   // 16 KB
    float* sc                = (float*)(ws + (20u << 20) + (1u << 16));
    float* bi                = sc + 128;

    k_prep<<<1, 256, 0, stream>>>(Ww, Wb, gamma, beta, mean, var, Wt, sc, bi);
    k_proj<<<512, 256, 0, stream>>>(x, tw, tb, pw, pb, gw, gb,
                                    theta_hi, theta_lo, phi_hi, phi_lo, gT);
    k_attn<<<dim3(32, 8), 256, 0, stream>>>(theta_hi, theta_lo, phi_hi, phi_lo,
                                            gT, Wt, sc, bi, x, (float*)d_out);
}

// Round 3
// 173.369 us; speedup vs baseline: 1.2830x; 1.2830x over previous
//
#include <hip/hip_runtime.h>
#include <math.h>

typedef short v8s __attribute__((ext_vector_type(8)));
typedef float v4f __attribute__((ext_vector_type(4)));
typedef unsigned short v4u __attribute__((ext_vector_type(4)));

#define MFMA(a, b, c) __builtin_amdgcn_mfma_f32_16x16x32_bf16((a), (b), (c), 0, 0, 0)

__device__ __forceinline__ unsigned short f2bf(float f) {
    unsigned int u = __builtin_bit_cast(unsigned int, f);
    u += 0x7fffu + ((u >> 16) & 1u);   // round-to-nearest-even
    return (unsigned short)(u >> 16);
}
__device__ __forceinline__ float bf2f(unsigned short h) {
    return __builtin_bit_cast(float, ((unsigned int)h) << 16);
}

// ---------------------------------------------------------------- k_prep ----
__global__ __launch_bounds__(256) void k_prep(
    const float* __restrict__ Ww, const float* __restrict__ Wb,
    const float* __restrict__ gamma, const float* __restrict__ beta,
    const float* __restrict__ mean, const float* __restrict__ var,
    unsigned short* __restrict__ Wt, float* __restrict__ sc, float* __restrict__ bi)
{
    int t = threadIdx.x;
    #pragma unroll
    for (int rep = 0; rep < 32; ++rep) {
        int idx = rep * 256 + t;          // 64*128 = 8192 elements
        int d = idx >> 7, c = idx & 127;  // W_w is [64][128], coalesced read
        Wt[c * 64 + d] = f2bf(Ww[idx]);
    }
    if (t < 128) {
        float inv = gamma[t] * rsqrtf(var[t] + 1e-4f);
        sc[t] = inv;
        bi[t] = (Wb[t] - mean[t]) * inv + beta[t];
    }
}

// ---------------------------------------------------------------- k_proj ----
// fp32 projections; theta/phi written as SPLIT bf16 (hi + residual-lo) for
// high-precision QK^T; g transposed bf16 gT[b][64][4096].
__global__ __launch_bounds__(256) void k_proj(
    const float* __restrict__ x,
    const float* __restrict__ tw, const float* __restrict__ tb,
    const float* __restrict__ pw, const float* __restrict__ pb,
    const float* __restrict__ gw, const float* __restrict__ gb,
    unsigned short* __restrict__ theta_hi, unsigned short* __restrict__ theta_lo,
    unsigned short* __restrict__ phi_hi, unsigned short* __restrict__ phi_lo,
    unsigned short* __restrict__ gT)
{
    __shared__ __align__(16) float xl[64][132];   // +4 pad
    __shared__ __align__(16) float wl[64][68];
    const int t = threadIdx.x;
    const int tok0 = blockIdx.x * 64;

    #pragma unroll
    for (int rep = 0; rep < 8; ++rep) {           // stage x tile [64][128]
        int chunk = rep * 256 + t;
        int tk = chunk >> 5, k = (chunk & 31) * 4;
        *(float4*)&xl[tk][k] = *(const float4*)(x + (size_t)(tok0 + tk) * 128 + k);
    }
    const int tg = t >> 4, og = t & 15;

    for (int p = 0; p < 3; ++p) {
        const float* wmat = (p == 0) ? tw : (p == 1) ? pw : gw;
        const float* bias = (p == 0) ? tb : (p == 1) ? pb : gb;
        float acc[4][4] = {};
        #pragma unroll
        for (int kh = 0; kh < 2; ++kh) {
            __syncthreads();                      // prev compute done
            #pragma unroll
            for (int rep = 0; rep < 4; ++rep) {   // stage W half [64][64]
                int chunk = rep * 256 + t;
                int kk = chunk >> 4, o = (chunk & 15) * 4;
                *(float4*)&wl[kk][o] = *(const float4*)(wmat + (kh * 64 + kk) * 64 + o);
            }
            __syncthreads();
            #pragma unroll 4
            for (int k = 0; k < 64; ++k) {
                float4 wv = *(const float4*)&wl[k][og * 4];
                #pragma unroll
                for (int i = 0; i < 4; ++i) {
                    float xv = xl[tg * 4 + i][kh * 64 + k];
                    acc[i][0] = fmaf(xv, wv.x, acc[i][0]);
                    acc[i][1] = fmaf(xv, wv.y, acc[i][1]);
                    acc[i][2] = fmaf(xv, wv.z, acc[i][2]);
                    acc[i][3] = fmaf(xv, wv.w, acc[i][3]);
                }
            }
        }
        float4 bv = *(const float4*)(bias + og * 4);
        const float bvv[4] = {bv.x, bv.y, bv.z, bv.w};
        if (p < 2) {
            unsigned short* dh = (p == 0) ? theta_hi : phi_hi;
            unsigned short* dl = (p == 0) ? theta_lo : phi_lo;
            #pragma unroll
            for (int i = 0; i < 4; ++i) {
                int tok = tok0 + tg * 4 + i;
                v4u oh, ol;
                #pragma unroll
                for (int j = 0; j < 4; ++j) {
                    float v = acc[i][j] + bvv[j];
                    unsigned short h = f2bf(v);
                    oh[j] = h;
                    ol[j] = f2bf(v - bf2f(h));
                }
                *(v4u*)(dh + (size_t)tok * 64 + og * 4) = oh;
                *(v4u*)(dl + (size_t)tok * 64 + og * 4) = ol;
            }
        } else {
            #pragma unroll
            for (int i = 0; i < 4; ++i) {
                int tok = tok0 + tg * 4 + i;
                int bb = tok >> 12, n = tok & 4095;
                #pragma unroll
                for (int j = 0; j < 4; ++j)
                    gT[((size_t)bb * 64 + og * 4 + j) * 4096 + n] = f2bf(acc[i][j] + bvv[j]);
            }
        }
    }
}

// ---------------------------------------------------------------- k_attn ----
// Flash attention + fused epilogue. Grid (32,8) = 256 blocks (1/CU),
// 512 threads = 8 waves x 16 queries (2 waves/SIMD for latency hiding).
// Key tile 64; mfma 16x16x32 bf16.
// QK^T uses split bf16: S = th_hi.ph_hi + th_hi.ph_lo + th_lo.ph_hi
// A-frag: row=l&15, k=(l>>4)*8+j ; B-frag: col=l&15, k=(l>>4)*8+j ;
// D: col=l&15, row=(l>>4)*4+r
__global__ __launch_bounds__(512, 1) void k_attn(
    const unsigned short* __restrict__ theta_hi,
    const unsigned short* __restrict__ theta_lo,
    const unsigned short* __restrict__ phi_hi,
    const unsigned short* __restrict__ phi_lo,
    const unsigned short* __restrict__ gT,
    const unsigned short* __restrict__ Wt,
    const float* __restrict__ sc, const float* __restrict__ bi,
    const float* __restrict__ x, float* __restrict__ out)
{
    __shared__ __align__(16) unsigned short ph_l[64][72];    // keys x dims (hi)
    __shared__ __align__(16) unsigned short pl_l[64][72];    // keys x dims (lo)
    __shared__ __align__(16) unsigned short gT_l[64][72];    // dims x keys
    __shared__ __align__(16) unsigned short scr[8][16][72];  // per-wave P / y
    __shared__ __align__(16) unsigned short Wt_l[128][72];   // W^T bf16

    const int t = threadIdx.x;
    const int w = t >> 6, l = t & 63, hi = l >> 4, lo = l & 15;
    const int b = blockIdx.y, qb = blockIdx.x;
    const int q0 = qb * 128 + w * 16;
    const size_t tok0 = (size_t)b * 4096 + q0;

    #pragma unroll
    for (int rep = 0; rep < 2; ++rep) {          // stage W^T once (128x64)
        int flat = rep * 4096 + t * 8;
        int c = flat >> 6, d = flat & 63;
        *(v8s*)&Wt_l[c][d] = *(const v8s*)(Wt + flat);
    }

    v8s thA[2], tlA[2];                          // hoisted Q fragments (hi, lo)
    #pragma unroll
    for (int kc = 0; kc < 2; ++kc) {
        size_t off = (tok0 + lo) * 64 + kc * 32 + hi * 8;
        thA[kc] = *(const v8s*)(theta_hi + off);
        tlA[kc] = *(const v8s*)(theta_lo + off);
    }

    const unsigned short* phb = phi_hi + (size_t)b * 4096 * 64;
    const unsigned short* plb = phi_lo + (size_t)b * 4096 * 64;
    const unsigned short* gTb = gT + (size_t)b * 64 * 4096;

    v4f yacc[4];
    float mrow[4], lrow[4];
    #pragma unroll
    for (int rr = 0; rr < 4; ++rr) {
        mrow[rr] = -INFINITY; lrow[rr] = 0.f;
        yacc[rr] = (v4f){0.f, 0.f, 0.f, 0.f};
    }

    // register prefetch of tile 0 (512 threads: 1 v8s per array per thread)
    const int rB = t >> 3, cB = (t & 7) * 8;
    v8s pfH = *(const v8s*)(phb + (size_t)rB * 64 + cB);
    v8s pfL = *(const v8s*)(plb + (size_t)rB * 64 + cB);
    v8s pfG = *(const v8s*)(gTb + (size_t)rB * 4096 + cB);

    for (int kt = 0; kt < 64; ++kt) {
        __syncthreads();                         // prev tile consumed
        *(v8s*)&ph_l[rB][cB] = pfH;
        *(v8s*)&pl_l[rB][cB] = pfL;
        *(v8s*)&gT_l[rB][cB] = pfG;
        __syncthreads();
        if (kt < 63) {                           // prefetch next tile under compute
            int kb2 = (kt + 1) * 64;
            pfH = *(const v8s*)(phb + (size_t)(kb2 + rB) * 64 + cB);
            pfL = *(const v8s*)(plb + (size_t)(kb2 + rB) * 64 + cB);
            pfG = *(const v8s*)(gTb + (size_t)rB * 4096 + kb2 + cB);
        }
        // ---- QK^T (split precision): S[s] = theta(16q) . phi(64k)^T
        v4f S[4];
        #pragma unroll
        for (int s = 0; s < 4; ++s) {
            v8s bH[2], bL[2];
            #pragma unroll
            for (int kc = 0; kc < 2; ++kc) {
                bH[kc] = *(const v8s*)&ph_l[s * 16 + lo][kc * 32 + hi * 8];
                bL[kc] = *(const v8s*)&pl_l[s * 16 + lo][kc * 32 + hi * 8];
            }
            v4f a = MFMA(thA[0], bH[0], ((v4f){0.f, 0.f, 0.f, 0.f}));
            a = MFMA(thA[1], bH[1], a);
            a = MFMA(thA[0], bL[0], a);
            a = MFMA(thA[1], bL[1], a);
            a = MFMA(tlA[0], bH[0], a);
            S[s] = MFMA(tlA[1], bH[1], a);
        }
        // ---- online softmax (rows spread over 16-lane groups; 4 rows/lane)
        float al[4];
        #pragma unroll
        for (int rr = 0; rr < 4; ++rr) {
            float v = fmaxf(fmaxf(S[0][rr], S[1][rr]), fmaxf(S[2][rr], S[3][rr]));
            v = fmaxf(v, __shfl_xor(v, 1));
            v = fmaxf(v, __shfl_xor(v, 2));
            v = fmaxf(v, __shfl_xor(v, 4));
            v = fmaxf(v, __shfl_xor(v, 8));
            float mo = mrow[rr];
            float mn = fmaxf(mo, v);
            float a = __expf(mo - mn);           // 0 on first tile (mo=-inf)
            mrow[rr] = mn;
            float p0 = __expf(S[0][rr] - mn);
            float p1 = __expf(S[1][rr] - mn);
            float p2 = __expf(S[2][rr] - mn);
            float p3 = __expf(S[3][rr] - mn);
            S[0][rr] = p0; S[1][rr] = p1; S[2][rr] = p2; S[3][rr] = p3;
            float sum = (p0 + p1) + (p2 + p3);
            sum += __shfl_xor(sum, 1);
            sum += __shfl_xor(sum, 2);
            sum += __shfl_xor(sum, 4);
            sum += __shfl_xor(sum, 8);
            lrow[rr] = lrow[rr] * a + sum;
            al[rr] = a;
        }
        // ---- P -> LDS (bf16, per-wave scratch), rescale accumulator
        unsigned short* pl = &scr[w][0][0];
        #pragma unroll
        for (int rr = 0; rr < 4; ++rr) {
            int m = hi * 4 + rr;
            #pragma unroll
            for (int s = 0; s < 4; ++s)
                pl[m * 72 + s * 16 + lo] = f2bf(S[s][rr]);
        }
        #pragma unroll
        for (int dt = 0; dt < 4; ++dt)
            #pragma unroll
            for (int rr = 0; rr < 4; ++rr)
                yacc[dt][rr] *= al[rr];
        // ---- PV: y += P(16q x 64k) . g(64k x 64d)
        v8s pA[2];
        #pragma unroll
        for (int kc = 0; kc < 2; ++kc)
            pA[kc] = *(const v8s*)&scr[w][lo][kc * 32 + hi * 8];
        #pragma unroll
        for (int kc = 0; kc < 2; ++kc)
            #pragma unroll
            for (int dt = 0; dt < 4; ++dt) {
                v8s gB = *(const v8s*)&gT_l[dt * 16 + lo][kc * 32 + hi * 8];
                yacc[dt] = MFMA(pA[kc], gB, yacc[dt]);
            }
    }

    // ---- epilogue: y/l -> bf16 LDS -> wy = y @ W^T -> BN + residual
    unsigned short* yl = &scr[w][0][0];
    #pragma unroll
    for (int rr = 0; rr < 4; ++rr) {
        float inv = 1.0f / lrow[rr];
        int m = hi * 4 + rr;
        #pragma unroll
        for (int dt = 0; dt < 4; ++dt)
            yl[m * 72 + dt * 16 + lo] = f2bf(yacc[dt][rr] * inv);
    }
    v8s yA[2];
    #pragma unroll
    for (int kc = 0; kc < 2; ++kc)
        yA[kc] = *(const v8s*)&scr[w][lo][kc * 32 + hi * 8];

    const float* xb = x + tok0 * 128;
    float* ob = out + tok0 * 128;
    #pragma unroll
    for (int ct = 0; ct < 8; ++ct) {
        v8s wB0 = *(const v8s*)&Wt_l[ct * 16 + lo][hi * 8];
        v8s wB1 = *(const v8s*)&Wt_l[ct * 16 + lo][32 + hi * 8];
        int c = ct * 16 + lo;
        float scc = sc[c], bic = bi[c];
        v4f wy = MFMA(yA[0], wB0, ((v4f){0.f, 0.f, 0.f, 0.f}));
        wy = MFMA(yA[1], wB1, wy);
        #pragma unroll
        for (int rr = 0; rr < 4; ++rr) {
            int m = hi * 4 + rr;
            ob[(size_t)m * 128 + c] = wy[rr] * scc + bic + xb[(size_t)m * 128 + c];
        }
    }
}

// ------------------------------------------------------------------ launch --
extern "C" void kernel_launch(void* const* d_in, const int* in_sizes, int n_in,
                              void* d_out, int out_size, void* d_ws, size_t ws_size,
                              hipStream_t stream) {
    const float* x     = (const float*)d_in[0];
    const float* tw    = (const float*)d_in[1];
    const float* tb    = (const float*)d_in[2];
    const float* pw    = (const float*)d_in[3];
    const float* pb    = (const float*)d_in[4];
    const float* gw    = (const float*)d_in[5];
    const float* gb    = (const float*)d_in[6];
    const float* Ww    = (const float*)d_in[7];
    const float* Wb    = (const float*)d_in[8];
    const float* gamma = (const float*)d_in[9];
    const float* beta  = (const float*)d_in[10];
    const float* mean  = (const float*)d_in[11];
    const float* var   = (const float*)d_in[12];

    char* ws = (char*)d_ws;
    unsigned short* theta_hi = (unsigned short*)ws;                   // 4 MB
    unsigned short* theta_lo = (unsigned short*)(ws + (4u << 20));    // 4 MB
    unsigned short* phi_hi   = (unsigned short*)(ws + (8u << 20));    // 4 MB
    unsigned short* phi_lo   = (unsigned short*)(ws + (12u << 20));   // 4 MB
    unsigned short* gT       = (unsigned short*)(ws + (16u << 20));   // 4 MB
    unsigned short* Wt       = (unsigned short*)(ws + (20u << 20));   // 16 KB
    float* sc                = (float*)(ws + (20u << 20) + (1u << 16));
    float* bi                = sc + 128;

    k_prep<<<1, 256, 0, stream>>>(Ww, Wb, gamma, beta, mean, var, Wt, sc, bi);
    k_proj<<<512, 256, 0, stream>>>(x, tw, tb, pw, pb, gw, gb,
                                    theta_hi, theta_lo, phi_hi, phi_lo, gT);
    k_attn<<<dim3(32, 8), 512, 0, stream>>>(theta_hi, theta_lo, phi_hi, phi_lo,
                                            gT, Wt, sc, bi, x, (float*)d_out);
}

// Round 4
// 130.370 us; speedup vs baseline: 1.7061x; 1.3298x over previous
//
#include <hip/hip_runtime.h>
#include <math.h>

typedef short v8s __attribute__((ext_vector_type(8)));
typedef float v4f __attribute__((ext_vector_type(4)));
typedef unsigned short v4u __attribute__((ext_vector_type(4)));

#define MFMA(a, b, c) __builtin_amdgcn_mfma_f32_16x16x32_bf16((a), (b), (c), 0, 0, 0)

// swizzled tile addressing: linear [row][64 shorts] with byte^((row&7)<<4)
#define TADDR(row, colb) (((row) * 128 + (colb)) ^ (((row) & 7) << 4))

__device__ __forceinline__ unsigned short f2bf(float f) {
    unsigned int u = __builtin_bit_cast(unsigned int, f);
    u += 0x7fffu + ((u >> 16) & 1u);   // round-to-nearest-even
    return (unsigned short)(u >> 16);
}
__device__ __forceinline__ float bf2f(unsigned short h) {
    return __builtin_bit_cast(float, ((unsigned int)h) << 16);
}
__device__ __forceinline__ unsigned int cvtpk_bf16(float lo, float hi) {
    unsigned int r;
    asm("v_cvt_pk_bf16_f32 %0, %1, %2" : "=v"(r) : "v"(lo), "v"(hi));
    return r;
}

// ---------------------------------------------------------------- k_prep ----
__global__ __launch_bounds__(256) void k_prep(
    const float* __restrict__ Ww, const float* __restrict__ Wb,
    const float* __restrict__ gamma, const float* __restrict__ beta,
    const float* __restrict__ mean, const float* __restrict__ var,
    unsigned short* __restrict__ Wt, float* __restrict__ sc, float* __restrict__ bi)
{
    int t = threadIdx.x;
    #pragma unroll
    for (int rep = 0; rep < 32; ++rep) {
        int idx = rep * 256 + t;          // 64*128 = 8192 elements
        int d = idx >> 7, c = idx & 127;  // W_w is [64][128], coalesced read
        Wt[c * 64 + d] = f2bf(Ww[idx]);
    }
    if (t < 128) {
        float inv = gamma[t] * rsqrtf(var[t] + 1e-4f);
        sc[t] = inv;
        bi[t] = (Wb[t] - mean[t]) * inv + beta[t];
    }
}

// ---------------------------------------------------------------- k_proj ----
// fp32 projections; theta/phi written as SPLIT bf16 (hi + residual-lo) for
// high-precision QK^T; g transposed bf16 gT[b][64][4096].
__global__ __launch_bounds__(256) void k_proj(
    const float* __restrict__ x,
    const float* __restrict__ tw, const float* __restrict__ tb,
    const float* __restrict__ pw, const float* __restrict__ pb,
    const float* __restrict__ gw, const float* __restrict__ gb,
    unsigned short* __restrict__ theta_hi, unsigned short* __restrict__ theta_lo,
    unsigned short* __restrict__ phi_hi, unsigned short* __restrict__ phi_lo,
    unsigned short* __restrict__ gT)
{
    __shared__ __align__(16) float xl[64][132];   // +4 pad
    __shared__ __align__(16) float wl[64][68];
    const int t = threadIdx.x;
    const int tok0 = blockIdx.x * 64;

    #pragma unroll
    for (int rep = 0; rep < 8; ++rep) {           // stage x tile [64][128]
        int chunk = rep * 256 + t;
        int tk = chunk >> 5, k = (chunk & 31) * 4;
        *(float4*)&xl[tk][k] = *(const float4*)(x + (size_t)(tok0 + tk) * 128 + k);
    }
    const int tg = t >> 4, og = t & 15;

    for (int p = 0; p < 3; ++p) {
        const float* wmat = (p == 0) ? tw : (p == 1) ? pw : gw;
        const float* bias = (p == 0) ? tb : (p == 1) ? pb : gb;
        float acc[4][4] = {};
        #pragma unroll
        for (int kh = 0; kh < 2; ++kh) {
            __syncthreads();                      // prev compute done
            #pragma unroll
            for (int rep = 0; rep < 4; ++rep) {   // stage W half [64][64]
                int chunk = rep * 256 + t;
                int kk = chunk >> 4, o = (chunk & 15) * 4;
                *(float4*)&wl[kk][o] = *(const float4*)(wmat + (kh * 64 + kk) * 64 + o);
            }
            __syncthreads();
            #pragma unroll 4
            for (int k = 0; k < 64; ++k) {
                float4 wv = *(const float4*)&wl[k][og * 4];
                #pragma unroll
                for (int i = 0; i < 4; ++i) {
                    float xv = xl[tg * 4 + i][kh * 64 + k];
                    acc[i][0] = fmaf(xv, wv.x, acc[i][0]);
                    acc[i][1] = fmaf(xv, wv.y, acc[i][1]);
                    acc[i][2] = fmaf(xv, wv.z, acc[i][2]);
                    acc[i][3] = fmaf(xv, wv.w, acc[i][3]);
                }
            }
        }
        float4 bv = *(const float4*)(bias + og * 4);
        const float bvv[4] = {bv.x, bv.y, bv.z, bv.w};
        if (p < 2) {
            unsigned short* dh = (p == 0) ? theta_hi : phi_hi;
            unsigned short* dl = (p == 0) ? theta_lo : phi_lo;
            #pragma unroll
            for (int i = 0; i < 4; ++i) {
                int tok = tok0 + tg * 4 + i;
                v4u oh, ol;
                #pragma unroll
                for (int j = 0; j < 4; ++j) {
                    float v = acc[i][j] + bvv[j];
                    unsigned short h = f2bf(v);
                    oh[j] = h;
                    ol[j] = f2bf(v - bf2f(h));
                }
                *(v4u*)(dh + (size_t)tok * 64 + og * 4) = oh;
                *(v4u*)(dl + (size_t)tok * 64 + og * 4) = ol;
            }
        } else {
            #pragma unroll
            for (int i = 0; i < 4; ++i) {
                int tok = tok0 + tg * 4 + i;
                int bb = tok >> 12, n = tok & 4095;
                #pragma unroll
                for (int j = 0; j < 4; ++j)
                    gT[((size_t)bb * 64 + og * 4 + j) * 4096 + n] = f2bf(acc[i][j] + bvv[j]);
            }
        }
    }
}

// ---------------------------------------------------------------- k_attn ----
// Flash attention + fused epilogue. Grid (32,8) = 256 blocks (1/CU),
// 512 threads = 8 waves x 16 queries.
// SWAPPED QK^T: S = MFMA(A=phi, B=theta) -> D col(l&15)=query, row=key.
// Each lane owns one query's P-slice (16 keys) -> in-lane softmax + 2 shuffles.
// All LDS tiles linear [row][64] with XOR swizzle byte^((row&7)<<4).
__global__ __launch_bounds__(512, 1) void k_attn(
    const unsigned short* __restrict__ theta_hi,
    const unsigned short* __restrict__ theta_lo,
    const unsigned short* __restrict__ phi_hi,
    const unsigned short* __restrict__ phi_lo,
    const unsigned short* __restrict__ gT,
    const unsigned short* __restrict__ Wt,
    const float* __restrict__ sc, const float* __restrict__ bi,
    const float* __restrict__ x, float* __restrict__ out)
{
    __shared__ __align__(16) unsigned short ph_l[64 * 64];   // keys x dims (hi)
    __shared__ __align__(16) unsigned short pl_l[64 * 64];   // keys x dims (lo)
    __shared__ __align__(16) unsigned short gT_l[64 * 64];   // dims x keys
    __shared__ __align__(16) unsigned short scr[8][16 * 64]; // per-wave P / y
    __shared__ __align__(16) unsigned short Wt_l[128][72];   // W^T bf16 (padded)

    const int t = threadIdx.x;
    const int w = t >> 6, l = t & 63, hi = l >> 4, lo = l & 15;
    const int b = blockIdx.y, qb = blockIdx.x;
    const int q0 = qb * 128 + w * 16;
    const size_t tok0 = (size_t)b * 4096 + q0;

    char* phc = (char*)ph_l;
    char* plc = (char*)pl_l;
    char* gTc = (char*)gT_l;
    char* scrc = (char*)&scr[w][0];

    #pragma unroll
    for (int rep = 0; rep < 2; ++rep) {          // stage W^T once (128x64)
        int flat = rep * 4096 + t * 8;
        int c = flat >> 6, d = flat & 63;
        *(v8s*)&Wt_l[c][d] = *(const v8s*)(Wt + flat);
    }

    v8s thA[2], tlA[2];                          // hoisted Q fragments (hi, lo)
    #pragma unroll
    for (int kc = 0; kc < 2; ++kc) {
        size_t off = (tok0 + lo) * 64 + kc * 32 + hi * 8;
        thA[kc] = *(const v8s*)(theta_hi + off);
        tlA[kc] = *(const v8s*)(theta_lo + off);
    }

    const unsigned short* phb = phi_hi + (size_t)b * 4096 * 64;
    const unsigned short* plb = phi_lo + (size_t)b * 4096 * 64;
    const unsigned short* gTb = gT + (size_t)b * 64 * 4096;

    v4f yacc[4];                                 // y[q'=4hi+rr][d=16dt+lo]
    #pragma unroll
    for (int dt = 0; dt < 4; ++dt) yacc[dt] = (v4f){0.f, 0.f, 0.f, 0.f};
    float mrow = -INFINITY, lrow = 0.f;          // per-lane: query q = lo

    // register prefetch of tile 0; staging lane -> tile row rB, 16B chunk cB
    const int rB = t >> 3, cB = (t & 7) * 8;     // cB in shorts
    const int stByte = TADDR(rB, cB * 2);        // swizzled LDS byte offset
    v8s pfH = *(const v8s*)(phb + (size_t)rB * 64 + cB);
    v8s pfL = *(const v8s*)(plb + (size_t)rB * 64 + cB);
    v8s pfG = *(const v8s*)(gTb + (size_t)rB * 4096 + cB);

    for (int kt = 0; kt < 64; ++kt) {
        __syncthreads();                         // prev tile consumed
        *(v8s*)(phc + stByte) = pfH;
        *(v8s*)(plc + stByte) = pfL;
        *(v8s*)(gTc + stByte) = pfG;
        __syncthreads();
        if (kt < 63) {                           // prefetch next tile under compute
            int kb2 = (kt + 1) * 64;
            pfH = *(const v8s*)(phb + (size_t)(kb2 + rB) * 64 + cB);
            pfL = *(const v8s*)(plb + (size_t)(kb2 + rB) * 64 + cB);
            pfG = *(const v8s*)(gTb + (size_t)rB * 4096 + kb2 + cB);
        }
        // ---- QK^T swapped (split precision): lane -> S[key=16s+4hi+rr][q=lo]
        v4f S[4];
        #pragma unroll
        for (int s = 0; s < 4; ++s) {
            v8s bH[2], bL[2];
            #pragma unroll
            for (int kc = 0; kc < 2; ++kc) {
                int byt = TADDR(s * 16 + lo, kc * 64 + hi * 16);
                bH[kc] = *(const v8s*)(phc + byt);
                bL[kc] = *(const v8s*)(plc + byt);
            }
            v4f a = MFMA(bH[0], thA[0], ((v4f){0.f, 0.f, 0.f, 0.f}));
            a = MFMA(bH[1], thA[1], a);
            a = MFMA(bL[0], thA[0], a);
            a = MFMA(bL[1], thA[1], a);
            a = MFMA(bH[0], tlA[0], a);
            S[s] = MFMA(bH[1], tlA[1], a);
        }
        // ---- online softmax: in-lane tree + xor16/xor32 (4 hi-lanes per query)
        float ms0 = fmaxf(fmaxf(S[0][0], S[0][1]), fmaxf(S[0][2], S[0][3]));
        float ms1 = fmaxf(fmaxf(S[1][0], S[1][1]), fmaxf(S[1][2], S[1][3]));
        float ms2 = fmaxf(fmaxf(S[2][0], S[2][1]), fmaxf(S[2][2], S[2][3]));
        float ms3 = fmaxf(fmaxf(S[3][0], S[3][1]), fmaxf(S[3][2], S[3][3]));
        float vmax = fmaxf(fmaxf(ms0, ms1), fmaxf(ms2, ms3));
        vmax = fmaxf(vmax, __shfl_xor(vmax, 16));
        vmax = fmaxf(vmax, __shfl_xor(vmax, 32));
        float a = 1.0f;
        if (!__all(vmax <= mrow + 8.0f)) {       // defer-max (THR=8)
            float mn = fmaxf(mrow, vmax);
            a = __expf(mrow - mn);               // 0 on first tile
            mrow = mn;
            float aq[4];
            #pragma unroll
            for (int rr = 0; rr < 4; ++rr)
                aq[rr] = __shfl(a, 20 * hi + rr);    // a of query 4hi+rr
            #pragma unroll
            for (int dt = 0; dt < 4; ++dt)
                #pragma unroll
                for (int rr = 0; rr < 4; ++rr)
                    yacc[dt][rr] *= aq[rr];
        }
        float psum = 0.f;
        #pragma unroll
        for (int s = 0; s < 4; ++s) {
            float p0 = __expf(S[s][0] - mrow);
            float p1 = __expf(S[s][1] - mrow);
            float p2 = __expf(S[s][2] - mrow);
            float p3 = __expf(S[s][3] - mrow);
            S[s][0] = p0; S[s][1] = p1; S[s][2] = p2; S[s][3] = p3;
            psum += (p0 + p1) + (p2 + p3);
        }
        psum += __shfl_xor(psum, 16);
        psum += __shfl_xor(psum, 32);
        lrow = lrow * a + psum;
        // ---- P -> scr packed b64: row = query lo, keys 16s+4hi..+3
        #pragma unroll
        for (int s = 0; s < 4; ++s) {
            uint2 pk;
            pk.x = cvtpk_bf16(S[s][0], S[s][1]);
            pk.y = cvtpk_bf16(S[s][2], S[s][3]);
            *(uint2*)(scrc + TADDR(lo, s * 32 + hi * 8)) = pk;
        }
        // ---- PV: y += P(16q x 64k) . g(64k x 64d)
        v8s pA[2];
        #pragma unroll
        for (int kc = 0; kc < 2; ++kc)
            pA[kc] = *(const v8s*)(scrc + TADDR(lo, kc * 64 + hi * 16));
        #pragma unroll
        for (int kc = 0; kc < 2; ++kc)
            #pragma unroll
            for (int dt = 0; dt < 4; ++dt) {
                v8s gB = *(const v8s*)(gTc + TADDR(dt * 16 + lo, kc * 64 + hi * 16));
                yacc[dt] = MFMA(pA[kc], gB, yacc[dt]);
            }
    }

    // ---- epilogue: y/l -> bf16 scr -> wy = y @ W^T -> BN + residual
    float lq[4];
    #pragma unroll
    for (int rr = 0; rr < 4; ++rr)
        lq[rr] = __shfl(lrow, 20 * hi + rr);     // lrow of query 4hi+rr
    #pragma unroll
    for (int rr = 0; rr < 4; ++rr) {
        float inv = 1.0f / lq[rr];
        int m = hi * 4 + rr;                     // query row
        #pragma unroll
        for (int dt = 0; dt < 4; ++dt)
            *(unsigned short*)(scrc + TADDR(m, (dt * 16 + lo) * 2)) =
                f2bf(yacc[dt][rr] * inv);
    }
    v8s yA[2];
    #pragma unroll
    for (int kc = 0; kc < 2; ++kc)
        yA[kc] = *(const v8s*)(scrc + TADDR(lo, kc * 64 + hi * 16));

    const float* xb = x + tok0 * 128;
    float* ob = out + tok0 * 128;
    #pragma unroll
    for (int ct = 0; ct < 8; ++ct) {
        v8s wB0 = *(const v8s*)&Wt_l[ct * 16 + lo][hi * 8];
        v8s wB1 = *(const v8s*)&Wt_l[ct * 16 + lo][32 + hi * 8];
        int c = ct * 16 + lo;
        float scc = sc[c], bic = bi[c];
        v4f wy = MFMA(yA[0], wB0, ((v4f){0.f, 0.f, 0.f, 0.f}));
        wy = MFMA(yA[1], wB1, wy);
        #pragma unroll
        for (int rr = 0; rr < 4; ++rr) {
            int m = hi * 4 + rr;
            ob[(size_t)m * 128 + c] = wy[rr] * scc + bic + xb[(size_t)m * 128 + c];
        }
    }
}

// ------------------------------------------------------------------ launch --
extern "C" void kernel_launch(void* const* d_in, const int* in_sizes, int n_in,
                              void* d_out, int out_size, void* d_ws, size_t ws_size,
                              hipStream_t stream) {
    const float* x     = (const float*)d_in[0];
    const float* tw    = (const float*)d_in[1];
    const float* tb    = (const float*)d_in[2];
    const float* pw    = (const float*)d_in[3];
    const float* pb    = (const float*)d_in[4];
    const float* gw    = (const float*)d_in[5];
    const float* gb    = (const float*)d_in[6];
    const float* Ww    = (const float*)d_in[7];
    const float* Wb    = (const float*)d_in[8];
    const float* gamma = (const float*)d_in[9];
    const float* beta  = (const float*)d_in[10];
    const float* mean  = (const float*)d_in[11];
    const float* var   = (const float*)d_in[12];

    char* ws = (char*)d_ws;
    unsigned short* theta_hi = (unsigned short*)ws;                   // 4 MB
    unsigned short* theta_lo = (unsigned short*)(ws + (4u << 20));    // 4 MB
    unsigned short* phi_hi   = (unsigned short*)(ws + (8u << 20));    // 4 MB
    unsigned short* phi_lo   = (unsigned short*)(ws + (12u << 20));   // 4 MB
    unsigned short* gT       = (unsigned short*)(ws + (16u << 20));   // 4 MB
    unsigned short* Wt       = (unsigned short*)(ws + (20u << 20));   // 16 KB
    float* sc                = (float*)(ws + (20u << 20) + (1u << 16));
    float* bi                = sc + 128;

    k_prep<<<1, 256, 0, stream>>>(Ww, Wb, gamma, beta, mean, var, Wt, sc, bi);
    k_proj<<<512, 256, 0, stream>>>(x, tw, tb, pw, pb, gw, gb,
                                    theta_hi, theta_lo, phi_hi, phi_lo, gT);
    k_attn<<<dim3(32, 8), 512, 0, stream>>>(theta_hi, theta_lo, phi_hi, phi_lo,
                                            gT, Wt, sc, bi, x, (float*)d_out);
}

// Round 6
// 103.890 us; speedup vs baseline: 2.1409x; 1.2549x over previous
//
#include <hip/hip_runtime.h>
#include <math.h>

typedef _Float16 v8h __attribute__((ext_vector_type(8)));
typedef _Float16 v4h __attribute__((ext_vector_type(4)));
typedef float v4f __attribute__((ext_vector_type(4)));

#define MFMA16(a, b, c) __builtin_amdgcn_mfma_f32_16x16x32_f16((a), (b), (c), 0, 0, 0)

// swizzled tile addressing (byte offsets)
// rows of 64 fp16 (128 B):  XOR 16B-slot with row&7
#define TA64(row, colb)  ((((row) * 128) + (colb)) ^ (((row) & 7) << 4))
// rows of 128 fp16 (256 B): XOR 16B-slot with row&15
#define TA128(row, colb) ((((row) * 256) + (colb)) ^ (((row) & 15) << 4))

__device__ __forceinline__ unsigned int pk_f16(float a, float b) {
    return __builtin_bit_cast(unsigned int, __builtin_amdgcn_cvt_pkrtz(a, b));
}

// ---------------------------------------------------------------- k_prep ----
// Wt[c][d] = fp16(W_w[d][c]); sc/bi fold conv-bias + BN.
__global__ __launch_bounds__(256) void k_prep(
    const float* __restrict__ Ww, const float* __restrict__ Wb,
    const float* __restrict__ gamma, const float* __restrict__ beta,
    const float* __restrict__ mean, const float* __restrict__ var,
    _Float16* __restrict__ Wt, float* __restrict__ sc, float* __restrict__ bi)
{
    int t = threadIdx.x;
    #pragma unroll
    for (int rep = 0; rep < 32; ++rep) {
        int idx = rep * 256 + t;          // 64*128 = 8192 elements
        int d = idx >> 7, c = idx & 127;  // W_w is [64][128], coalesced read
        Wt[c * 64 + d] = (_Float16)Ww[idx];
    }
    if (t < 128) {
        float inv = gamma[t] * rsqrtf(var[t] + 1e-4f);
        sc[t] = inv;
        bi[t] = (Wb[t] - mean[t]) * inv + beta[t];
    }
}

// ---------------------------------------------------------------- k_proj ----
// fp32 projections (precision-critical), outputs fp16:
// theta/phi token-major [32768][64]; g transposed gT[b][64][4096].
__global__ __launch_bounds__(256) void k_proj(
    const float* __restrict__ x,
    const float* __restrict__ tw, const float* __restrict__ tb,
    const float* __restrict__ pw, const float* __restrict__ pb,
    const float* __restrict__ gw, const float* __restrict__ gb,
    _Float16* __restrict__ theta, _Float16* __restrict__ phi,
    _Float16* __restrict__ gT)
{
    __shared__ __align__(16) float xl[64][132];   // +4 pad
    __shared__ __align__(16) float wl[64][68];
    const int t = threadIdx.x;
    const int tok0 = blockIdx.x * 64;

    #pragma unroll
    for (int rep = 0; rep < 8; ++rep) {           // stage x tile [64][128]
        int chunk = rep * 256 + t;
        int tk = chunk >> 5, k = (chunk & 31) * 4;
        *(float4*)&xl[tk][k] = *(const float4*)(x + (size_t)(tok0 + tk) * 128 + k);
    }
    const int tg = t >> 4, og = t & 15;

    for (int p = 0; p < 3; ++p) {
        const float* wmat = (p == 0) ? tw : (p == 1) ? pw : gw;
        const float* bias = (p == 0) ? tb : (p == 1) ? pb : gb;
        float acc[4][4] = {};
        #pragma unroll
        for (int kh = 0; kh < 2; ++kh) {
            __syncthreads();                      // prev compute done
            #pragma unroll
            for (int rep = 0; rep < 4; ++rep) {   // stage W half [64][64]
                int chunk = rep * 256 + t;
                int kk = chunk >> 4, o = (chunk & 15) * 4;
                *(float4*)&wl[kk][o] = *(const float4*)(wmat + (kh * 64 + kk) * 64 + o);
            }
            __syncthreads();
            #pragma unroll 4
            for (int k = 0; k < 64; ++k) {
                float4 wv = *(const float4*)&wl[k][og * 4];
                #pragma unroll
                for (int i = 0; i < 4; ++i) {
                    float xv = xl[tg * 4 + i][kh * 64 + k];
                    acc[i][0] = fmaf(xv, wv.x, acc[i][0]);
                    acc[i][1] = fmaf(xv, wv.y, acc[i][1]);
                    acc[i][2] = fmaf(xv, wv.z, acc[i][2]);
                    acc[i][3] = fmaf(xv, wv.w, acc[i][3]);
                }
            }
        }
        float4 bv = *(const float4*)(bias + og * 4);
        const float bvv[4] = {bv.x, bv.y, bv.z, bv.w};
        if (p < 2) {
            _Float16* dst = (p == 0) ? theta : phi;
            #pragma unroll
            for (int i = 0; i < 4; ++i) {
                int tok = tok0 + tg * 4 + i;
                v4h o4;
                #pragma unroll
                for (int j = 0; j < 4; ++j)
                    o4[j] = (_Float16)(acc[i][j] + bvv[j]);
                *(v4h*)(dst + (size_t)tok * 64 + og * 4) = o4;
            }
        } else {
            #pragma unroll
            for (int i = 0; i < 4; ++i) {
                int tok = tok0 + tg * 4 + i;
                int bb = tok >> 12, n = tok & 4095;
                #pragma unroll
                for (int j = 0; j < 4; ++j)
                    gT[((size_t)bb * 64 + og * 4 + j) * 4096 + n] =
                        (_Float16)(acc[i][j] + bvv[j]);
            }
        }
    }
}

// ---------------------------------------------------------------- k_attn ----
// Flash attention + fused epilogue, all-fp16 MFMA. Grid (32,8) = 256 blocks,
// 512 threads = 8 waves x 16 queries. Key tile 128 (32 iterations).
// SWAPPED QK^T: S = MFMA(A=phi, B=theta) -> lane owns query lo's P-slice.
// LDS tiles XOR-swizzled (TA64/TA128).
__global__ __launch_bounds__(512, 1) void k_attn(
    const _Float16* __restrict__ theta,
    const _Float16* __restrict__ phi,
    const _Float16* __restrict__ gT,
    const _Float16* __restrict__ Wt,
    const float* __restrict__ sc, const float* __restrict__ bi,
    const float* __restrict__ x, float* __restrict__ out)
{
    __shared__ __align__(16) _Float16 ph_l[128 * 64];    // keys x dims
    __shared__ __align__(16) _Float16 gv_l[64 * 128];    // dims x keys
    __shared__ __align__(16) _Float16 scr[8][16 * 128];  // per-wave P / y
    __shared__ __align__(16) _Float16 wt_l[128 * 64];    // W^T fp16

    const int t = threadIdx.x;
    const int w = t >> 6, l = t & 63, hi = l >> 4, lo = l & 15;
    const int b = blockIdx.y, qb = blockIdx.x;
    const int q0 = qb * 128 + w * 16;
    const size_t tok0 = (size_t)b * 4096 + q0;

    char* phL = (char*)ph_l;
    char* gvL = (char*)gv_l;
    char* wtL = (char*)wt_l;
    char* scrc = (char*)&scr[w][0];

    // stage W^T once: 128 rows x 64 fp16 = 1024 16B chunks, TA64-swizzled
    {
        int r0 = t >> 3, c0 = (t & 7) * 16;
        *(v8h*)(wtL + TA64(r0, c0)) = *(const v8h*)(Wt + r0 * 64 + (c0 >> 1));
        int r1 = r0 + 64;
        *(v8h*)(wtL + TA64(r1, c0)) = *(const v8h*)(Wt + r1 * 64 + (c0 >> 1));
    }

    v8h thA[2];                          // hoisted Q fragments
    #pragma unroll
    for (int kc = 0; kc < 2; ++kc)
        thA[kc] = *(const v8h*)(theta + (tok0 + lo) * 64 + kc * 32 + hi * 8);

    const _Float16* phb = phi + (size_t)b * 4096 * 64;
    const _Float16* gvb = gT + (size_t)b * 64 * 4096;

    v4f yacc[4];                         // y[q'=4hi+rr][d=16dt+lo]
    #pragma unroll
    for (int dt = 0; dt < 4; ++dt) yacc[dt] = (v4f){0.f, 0.f, 0.f, 0.f};
    float mrow = -INFINITY, lrow = 0.f;  // per-lane: query q = lo

    // staging map: ph 128x64 (8 chunks/row), gv 64x128 (16 chunks/row)
    const int phr = t >> 3, phcB = (t & 7) * 16;   // + row 64 second chunk
    const int gvr = t >> 4, gvcB = (t & 15) * 16;  // + row 32 second chunk
    const int phA0 = TA64(phr, phcB), phA1 = TA64(phr + 64, phcB);
    const int gvA0 = TA128(gvr, gvcB), gvA1 = TA128(gvr + 32, gvcB);
    const _Float16* pPh = phb + (size_t)phr * 64 + (phcB >> 1);
    const _Float16* pGv = gvb + (size_t)gvr * 4096 + (gvcB >> 1);

    // prefetch tile 0
    v8h pf0 = *(const v8h*)(pPh);
    v8h pf1 = *(const v8h*)(pPh + 64 * 64);
    v8h pf2 = *(const v8h*)(pGv);
    v8h pf3 = *(const v8h*)(pGv + (size_t)32 * 4096);
    pPh += 128 * 64; pGv += 128;

    for (int kt = 0; kt < 32; ++kt) {
        __syncthreads();                 // prev tile consumed
        *(v8h*)(phL + phA0) = pf0;
        *(v8h*)(phL + phA1) = pf1;
        *(v8h*)(gvL + gvA0) = pf2;
        *(v8h*)(gvL + gvA1) = pf3;
        __syncthreads();
        if (kt < 31) {                   // prefetch next tile under compute
            pf0 = *(const v8h*)(pPh);
            pf1 = *(const v8h*)(pPh + 64 * 64);
            pf2 = *(const v8h*)(pGv);
            pf3 = *(const v8h*)(pGv + (size_t)32 * 4096);
            pPh += 128 * 64; pGv += 128;
        }
        // ---- QK^T swapped: lane -> S[key=16s+4hi+rr][q=lo]
        v4f S[8];
        __builtin_amdgcn_s_setprio(1);
        #pragma unroll
        for (int s = 0; s < 8; ++s) {
            v8h a0 = *(const v8h*)(phL + TA64(s * 16 + lo, hi * 16));
            v8h a1 = *(const v8h*)(phL + TA64(s * 16 + lo, 64 + hi * 16));
            v4f acc = MFMA16(a0, thA[0], ((v4f){0.f, 0.f, 0.f, 0.f}));
            S[s] = MFMA16(a1, thA[1], acc);
        }
        __builtin_amdgcn_s_setprio(0);
        // ---- online softmax (in-lane tree + xor16/xor32)
        float vmax = -INFINITY;
        #pragma unroll
        for (int s = 0; s < 8; ++s)
            vmax = fmaxf(vmax, fmaxf(fmaxf(S[s][0], S[s][1]),
                                     fmaxf(S[s][2], S[s][3])));
        vmax = fmaxf(vmax, __shfl_xor(vmax, 16));
        vmax = fmaxf(vmax, __shfl_xor(vmax, 32));
        float a = 1.0f;
        if (!__all(vmax <= mrow + 8.0f)) {   // defer-max (THR=8)
            float mn = fmaxf(mrow, vmax);
            a = __expf(mrow - mn);           // 0 on first tile
            mrow = mn;
            float aq[4];
            #pragma unroll
            for (int rr = 0; rr < 4; ++rr)
                aq[rr] = __shfl(a, 20 * hi + rr);  // a of query 4hi+rr
            #pragma unroll
            for (int dt = 0; dt < 4; ++dt)
                #pragma unroll
                for (int rr = 0; rr < 4; ++rr)
                    yacc[dt][rr] *= aq[rr];
        }
        float psum = 0.f;
        #pragma unroll
        for (int s = 0; s < 8; ++s) {
            #pragma unroll
            for (int rr = 0; rr < 4; ++rr)
                S[s][rr] = __expf(S[s][rr] - mrow);
            psum += (S[s][0] + S[s][1]) + (S[s][2] + S[s][3]);
        }
        psum += __shfl_xor(psum, 16);
        psum += __shfl_xor(psum, 32);
        lrow = lrow * a + psum;
        // ---- P -> scr (fp16, packed b64): row = query lo, key 16s+4hi+rr
        #pragma unroll
        for (int s = 0; s < 8; ++s) {
            uint2 pk;
            pk.x = pk_f16(S[s][0], S[s][1]);
            pk.y = pk_f16(S[s][2], S[s][3]);
            *(uint2*)(scrc + TA128(lo, s * 32 + hi * 8)) = pk;
        }
        // ---- PV: y += P(16q x 128k) . g(128k x 64d)
        v8h pA[4];
        #pragma unroll
        for (int kc = 0; kc < 4; ++kc)
            pA[kc] = *(const v8h*)(scrc + TA128(lo, kc * 64 + hi * 16));
        __builtin_amdgcn_s_setprio(1);
        #pragma unroll
        for (int kc = 0; kc < 4; ++kc)
            #pragma unroll
            for (int dt = 0; dt < 4; ++dt) {
                v8h gB = *(const v8h*)(gvL + TA128(dt * 16 + lo, kc * 64 + hi * 16));
                yacc[dt] = MFMA16(pA[kc], gB, yacc[dt]);
            }
        __builtin_amdgcn_s_setprio(0);
    }

    // ---- epilogue: y/l -> fp16 scr -> wy = y @ W^T -> BN + residual
    float lq[4];
    #pragma unroll
    for (int rr = 0; rr < 4; ++rr)
        lq[rr] = __shfl(lrow, 20 * hi + rr);     // lrow of query 4hi+rr
    #pragma unroll
    for (int rr = 0; rr < 4; ++rr) {
        float inv = 1.0f / lq[rr];
        int m = hi * 4 + rr;                     // query row
        #pragma unroll
        for (int dt = 0; dt < 4; ++dt)
            *(_Float16*)(scrc + TA64(m, (dt * 16 + lo) * 2)) =
                (_Float16)(yacc[dt][rr] * inv);
    }
    v8h yA[2];
    #pragma unroll
    for (int kc = 0; kc < 2; ++kc)
        yA[kc] = *(const v8h*)(scrc + TA64(lo, kc * 64 + hi * 16));

    const float* xb = x + tok0 * 128;
    float* ob = out + tok0 * 128;
    #pragma unroll
    for (int ct = 0; ct < 8; ++ct) {
        v8h wB0 = *(const v8h*)(wtL + TA64(ct * 16 + lo, hi * 16));
        v8h wB1 = *(const v8h*)(wtL + TA64(ct * 16 + lo, 64 + hi * 16));
        int c = ct * 16 + lo;
        float scc = sc[c], bic = bi[c];
        v4f wy = MFMA16(yA[0], wB0, ((v4f){0.f, 0.f, 0.f, 0.f}));
        wy = MFMA16(yA[1], wB1, wy);
        #pragma unroll
        for (int rr = 0; rr < 4; ++rr) {
            int m = hi * 4 + rr;
            ob[(size_t)m * 128 + c] = wy[rr] * scc + bic + xb[(size_t)m * 128 + c];
        }
    }
}

// ------------------------------------------------------------------ launch --
extern "C" void kernel_launch(void* const* d_in, const int* in_sizes, int n_in,
                              void* d_out, int out_size, void* d_ws, size_t ws_size,
                              hipStream_t stream) {
    const float* x     = (const float*)d_in[0];
    const float* tw    = (const float*)d_in[1];
    const float* tb    = (const float*)d_in[2];
    const float* pw    = (const float*)d_in[3];
    const float* pb    = (const float*)d_in[4];
    const float* gw    = (const float*)d_in[5];
    const float* gb    = (const float*)d_in[6];
    const float* Ww    = (const float*)d_in[7];
    const float* Wb    = (const float*)d_in[8];
    const float* gamma = (const float*)d_in[9];
    const float* beta  = (const float*)d_in[10];
    const float* mean  = (const float*)d_in[11];
    const float* var   = (const float*)d_in[12];

    char* ws = (char*)d_ws;
    _Float16* theta = (_Float16*)ws;                   // 4 MB
    _Float16* phi   = (_Float16*)(ws + (4u << 20));    // 4 MB
    _Float16* gT    = (_Float16*)(ws + (8u << 20));    // 4 MB
    _Float16* Wt    = (_Float16*)(ws + (12u << 20));   // 16 KB
    float* sc       = (float*)(ws + (12u << 20) + (1u << 16));
    float* bi       = sc + 128;

    k_prep<<<1, 256, 0, stream>>>(Ww, Wb, gamma, beta, mean, var, Wt, sc, bi);
    k_proj<<<512, 256, 0, stream>>>(x, tw, tb, pw, pb, gw, gb, theta, phi, gT);
    k_attn<<<dim3(32, 8), 512, 0, stream>>>(theta, phi, gT, Wt, sc, bi,
                                            x, (float*)d_out);
}